// Round 3
// baseline (153.416 us; speedup 1.0000x reference)
//
#include <hip/hip_runtime.h>
#include <hip/hip_bf16.h>
#include <stdint.h>

typedef __attribute__((ext_vector_type(8))) short short8;
typedef __attribute__((ext_vector_type(4))) float floatx4;
typedef __attribute__((ext_vector_type(4))) unsigned int uintx4;
typedef __attribute__((ext_vector_type(2))) unsigned int uintx2;
typedef unsigned int u32;

#define HH 64
#define WW 64
#define HWSZ 4096
#define BB 8
#define CIN 256
#define COUT 256
#define NTOT 32768  // B*H*W

// async global->LDS DMA, 16 B per lane; LDS dest = wave-uniform base + lane*16
#define GLL16(g, l)                                                            \
    __builtin_amdgcn_global_load_lds(                                          \
        (const __attribute__((address_space(1))) u32*)(const void*)(g),        \
        (__attribute__((address_space(3))) u32*)(void*)(l), 16, 0, 0)

__device__ __forceinline__ unsigned short f2b(float f) {
    union { float f; unsigned int u; } v; v.f = f;
    unsigned int r = v.u + 0x7FFFu + ((v.u >> 16) & 1u);
    return (unsigned short)(r >> 16);
}
__device__ __forceinline__ float b2f(unsigned short h) {
    union { unsigned int u; float f; } v; v.u = ((unsigned int)h) << 16;
    return v.f;
}
// hw packed f32->bf16 (RNE, same result as f2b for finite inputs)
__device__ __forceinline__ unsigned int pk2(float lo, float hi) {
    unsigned int r;
    asm("v_cvt_pk_bf16_f32 %0, %1, %2" : "=v"(r) : "v"(lo), "v"(hi));
    return r;
}

// ---- weight cast ---- (unchanged)
__global__ void wcast(const float* __restrict__ wq, const float* __restrict__ wk,
                      const float* __restrict__ wv,
                      unsigned short* __restrict__ wqb, unsigned short* __restrict__ wkb,
                      unsigned short* __restrict__ wvb) {
    int idx = blockIdx.x * 256 + threadIdx.x;
    wqb[idx] = f2b(wq[idx]);
    wkb[idx] = f2b(wk[idx]);
    wvb[idx] = f2b(wv[idx]);
}

// ---- GEMM v7: 8x32-k pipeline, ONE counted-vmcnt barrier per chunk ----
// Out[m][n] = sum_k W[m][k] * In[k][n], In = x or y natural [b][c][hw] f32.
// Iteration it: compute chunk it from LDS buf[it&1]; stage chunk it+1 into
// buf[(it+1)&1] (A: GLL16 w/ pre-swizzled source; B: f32 regs (loaded 2 iters
// ago) -> cvt_pk -> swizzled ds_write); issue B f32 loads for chunk it+2.
// Raw s_barrier + counted s_waitcnt: B prefetch stays in flight across
// barriers (vmcnt never 0 in steady state). k order 0..7*32 identical to v6
// -> bitwise-identical output.
// LDS A swizzle: phys chunk p of row r holds W[r][8*(p ^ ((r>>1)&3))]
// (source pre-swizzle; GLL16 dest must stay linear). Read XORs the same.
__global__ __launch_bounds__(256)
void gemm_qkv(const unsigned short* __restrict__ wqb, const unsigned short* __restrict__ wkb,
              const unsigned short* __restrict__ wvb,
              const float* __restrict__ xf, const float* __restrict__ yf,
              unsigned short* __restrict__ Qb, unsigned short* __restrict__ Kb,
              unsigned short* __restrict__ Vb) {
    __shared__ unsigned short lA[2][128 * 32];   // 2 x 8 KB
    __shared__ unsigned short lB[2][128 * 32];   // 2 x 8 KB

    int z = blockIdx.z;
    const unsigned short* Wb = (z == 0) ? wqb : (z == 1) ? wkb : wvb;
    const float* In = (z == 0) ? yf : xf;
    unsigned short* Out = (z == 0) ? Qb : (z == 1) ? Kb : Vb;

    int n0 = blockIdx.x * 128;
    int m0 = blockIdx.y * 128;
    int bb = n0 >> 12;       // batch
    int p0 = n0 & 4095;      // pixel offset within batch
    int t = threadIdx.x;
    int lane = t & 63;
    int wave = t >> 6;
    int quad = lane >> 4;
    int l16 = lane & 15;
    int wm = (wave >> 1) * 64;
    int wn = (wave & 1) * 64;

    // ---- A staging: pre-swizzled global source, linear GLL16 dest ----
    int rA = t >> 2;                       // LDS row 0..63 (and +64 via gA1)
    int qA = t & 3;                        // phys 8-elem chunk within 32-k
    int cchA = 8 * (qA ^ ((rA >> 1) & 3)); // swizzled k-offset within chunk
    const unsigned short* gA0 = Wb + (size_t)(m0 + rA) * CIN + cchA;
    const unsigned short* gA1 = gA0 + (size_t)64 * CIN;   // (r+64>>1)&3 == (r>>1)&3

    // ---- B staging: thread owns 4 n x 4 k per 32-k chunk ----
    int sbase = t & 31;
    int ng = sbase * 4;
    int kq = (t >> 5) * 4;
    const float* gB = In + ((size_t)bb * CIN + kq) * HWSZ + p0 + ng;
    int wr_idx[4];
    #pragma unroll
    for (int j = 0; j < 4; ++j) {
        int s = j * 32 + sbase;            // LDS row s holds n = 4*(s&31)+(s>>5)
        wr_idx[j] = s * 32 + (((kq >> 3) ^ ((s >> 1) & 3)) << 3) + (kq & 4);
    }

    // ---- fragment read offsets (swizzle-aware) ----
    int swzA = (l16 >> 1) & 3;             // ((wm+mi*16+l16)>>1)&3, wm/mi-invariant
    int rBr = (wn >> 2) + l16;
    int swzB = (rBr >> 1) & 3;             // ni*32-invariant
    int rdA = (wm + l16) * 32 + ((quad ^ swzA) << 3);   // + mi*512
    int rdB = rBr * 32 + ((quad ^ swzB) << 3);          // + ni*1024

    floatx4 acc[4][4];
    #pragma unroll
    for (int mi = 0; mi < 4; ++mi)
        #pragma unroll
        for (int ni = 0; ni < 4; ++ni)
            acc[mi][ni] = (floatx4){0.f, 0.f, 0.f, 0.f};

    floatx4 bl[2][4];   // 2-deep B register pipeline (static indices only)

    // ---- prologue: chunk0 fully staged, chunk1 B-loads in flight ----
    #pragma unroll
    for (int i = 0; i < 4; ++i)
        bl[0][i] = *(const floatx4*)(gB + (size_t)i * HWSZ);            // L0 (4)
    __builtin_amdgcn_sched_barrier(0);
    GLL16(gA0, lA[0] + wave * 512);                                     // A0 (2)
    GLL16(gA1, lA[0] + wave * 512 + 2048);
    __builtin_amdgcn_sched_barrier(0);
    #pragma unroll
    for (int i = 0; i < 4; ++i)
        bl[1][i] = *(const floatx4*)(gB + (size_t)(32 + i) * HWSZ);     // L1 (4)
    asm volatile("s_waitcnt vmcnt(6)" ::: "memory");                    // L0 done
    #pragma unroll
    for (int j = 0; j < 4; ++j) {
        unsigned int d0 = pk2(bl[0][0][j], bl[0][1][j]);
        unsigned int d1 = pk2(bl[0][2][j], bl[0][3][j]);
        *(uintx2*)(lB[0] + wr_idx[j]) = (uintx2){d0, d1};
    }
    asm volatile("s_waitcnt vmcnt(4) lgkmcnt(0)" ::: "memory");         // A0 done
    __builtin_amdgcn_s_barrier();
    __builtin_amdgcn_sched_barrier(0);

    // ---- main loop: queue invariant at iter top = [L(it+1) (4)] ----
    #pragma unroll
    for (int it = 0; it < 8; ++it) {
        if (it < 7) {                                  // A(it+1) -> buf[(it+1)&1]
            GLL16(gA0 + (it + 1) * 32, lA[(it + 1) & 1] + wave * 512);
            GLL16(gA1 + (it + 1) * 32, lA[(it + 1) & 1] + wave * 512 + 2048);
        }
        __builtin_amdgcn_sched_barrier(0);             // pin A before L(it+2)
        if (it < 6) {                                  // B f32 for chunk it+2
            #pragma unroll
            for (int i = 0; i < 4; ++i)
                bl[it & 1][i] = *(const floatx4*)(gB + (size_t)((it + 2) * 32 + i) * HWSZ);
        }

        // MFMA on buf[it&1] (staged before previous barrier; no extra wait)
        short8 af[4], bf[4];
        #pragma unroll
        for (int mi = 0; mi < 4; ++mi)
            af[mi] = *(const short8*)(lA[it & 1] + rdA + mi * 512);
        #pragma unroll
        for (int ni = 0; ni < 4; ++ni)
            bf[ni] = *(const short8*)(lB[it & 1] + rdB + ni * 1024);
        #pragma unroll
        for (int mi = 0; mi < 4; ++mi)
            #pragma unroll
            for (int ni = 0; ni < 4; ++ni)
                acc[mi][ni] = __builtin_amdgcn_mfma_f32_16x16x32_bf16(af[mi], bf[ni], acc[mi][ni], 0, 0, 0);

        if (it < 7) {
            // wait B(it+1) regs (issued one full iteration ago)
            if (it < 6) { asm volatile("s_waitcnt vmcnt(6)" ::: "memory"); }
            else        { asm volatile("s_waitcnt vmcnt(2)" ::: "memory"); }
            #pragma unroll
            for (int j = 0; j < 4; ++j) {
                unsigned int d0 = pk2(bl[(it + 1) & 1][0][j], bl[(it + 1) & 1][1][j]);
                unsigned int d1 = pk2(bl[(it + 1) & 1][2][j], bl[(it + 1) & 1][3][j]);
                *(uintx2*)(lB[(it + 1) & 1] + wr_idx[j]) = (uintx2){d0, d1};
            }
            // A(it+1) done + ds_writes flushed; L(it+2) stays in flight
            if (it < 6) { asm volatile("s_waitcnt vmcnt(4) lgkmcnt(0)" ::: "memory"); }
            else        { asm volatile("s_waitcnt vmcnt(0) lgkmcnt(0)" ::: "memory"); }
            __builtin_amdgcn_s_barrier();
            __builtin_amdgcn_sched_barrier(0);
        }
    }

    // epilogue: lane owns cols n0+wn+4*l16 .. +3, rows wm+mi*16+quad*4+r (unchanged)
    int colb = n0 + wn + 4 * l16;
    #pragma unroll
    for (int mi = 0; mi < 4; ++mi) {
        #pragma unroll
        for (int r = 0; r < 4; ++r) {
            int row = m0 + wm + mi * 16 + quad * 4 + r;
            unsigned int lo = (unsigned int)f2b(acc[mi][0][r]) | ((unsigned int)f2b(acc[mi][1][r]) << 16);
            unsigned int hi = (unsigned int)f2b(acc[mi][2][r]) | ((unsigned int)f2b(acc[mi][3][r]) << 16);
            *(uintx2*)(Out + (size_t)row * NTOT + colb) = (uintx2){lo, hi};
        }
    }
}

// ---- attention v4: 8 outputs/thread, BRANCH-FREE clamped loads + cndmask ----
// (unchanged)
__global__ __launch_bounds__(256)
void attn(const unsigned short* __restrict__ Q,
          const unsigned short* __restrict__ K,
          const unsigned short* __restrict__ V,
          const float* __restrict__ rel_h,
          const float* __restrict__ rel_w,
          float* __restrict__ out) {
    int gid = blockIdx.x * 256 + threadIdx.x;
    int w8 = gid & 7;
    int w0 = w8 << 3;
    int h = (gid >> 3) & 63;
    int c = (gid >> 9) & 255;
    int b = gid >> 17;

    size_t nb = (size_t)c * NTOT + (size_t)b * HWSZ;
    const unsigned short* Kp = K + nb;
    const unsigned short* Vp = V + nb;

    short8 qr = *(const short8*)(Q + nb + h * 64 + w0);

    bool use_h = (c < 128);
    float rel3[3];
    if (use_h) {
        rel3[0] = rel_h[c * 3 + 0]; rel3[1] = rel_h[c * 3 + 1]; rel3[2] = rel_h[c * 3 + 2];
    } else {
        int cc = c - 128;
        rel3[0] = rel_w[cc * 3 + 0]; rel3[1] = rel_w[cc * 3 + 1]; rel3[2] = rel_w[cc * 3 + 2];
    }
    float rr[9];
    #pragma unroll
    for (int r = 0; r < 3; ++r)
        #pragma unroll
        for (int j = 0; j < 3; ++j)
            rr[r * 3 + j] = use_h ? rel3[r] : rel3[j];

    int e0 = (w0 > 0) ? w0 - 1 : 0;      // always in-row
    int e9 = (w0 < 56) ? w0 + 8 : 63;
    bool okL = (w0 > 0);
    bool okR = (w0 < 56);

    float kb[3][10], vb[3][10];
    #pragma unroll
    for (int r = 0; r < 3; ++r) {
        int ihr = h + r - 1;
        bool rok = (unsigned)ihr < 64u;
        int ihc = ihr < 0 ? 0 : (ihr > 63 ? 63 : ihr);
        int ro = ihc * 64;
        short8 km = *(const short8*)(Kp + ro + w0);
        short8 vm = *(const short8*)(Vp + ro + w0);
        float ke0 = b2f(Kp[ro + e0]), ve0 = b2f(Vp[ro + e0]);
        float ke9 = b2f(Kp[ro + e9]), ve9 = b2f(Vp[ro + e9]);
        #pragma unroll
        for (int i = 0; i < 8; ++i) {
            kb[r][i + 1] = rok ? b2f((unsigned short)km[i]) : 0.f;
            vb[r][i + 1] = rok ? b2f((unsigned short)vm[i]) : 0.f;
        }
        bool ok0 = rok && okL;
        bool ok9 = rok && okR;
        kb[r][0] = ok0 ? ke0 : 0.f;  vb[r][0] = ok0 ? ve0 : 0.f;
        kb[r][9] = ok9 ? ke9 : 0.f;  vb[r][9] = ok9 ? ve9 : 0.f;
    }

    float q[8];
    #pragma unroll
    for (int i = 0; i < 8; ++i) q[i] = b2f((unsigned short)qr[i]);

    float ov[8];
    #pragma unroll
    for (int wi = 0; wi < 8; ++wi) {
        float qv = q[wi];
        float lg[9];
        #pragma unroll
        for (int r = 0; r < 3; ++r)
            #pragma unroll
            for (int j = 0; j < 3; ++j)
                lg[r * 3 + j] = qv * (kb[r][wi + j] + rr[r * 3 + j]);
        float m = lg[0];
        #pragma unroll
        for (int t2 = 1; t2 < 9; ++t2) m = fmaxf(m, lg[t2]);
        float s = 0.f, o = 0.f;
        #pragma unroll
        for (int r = 0; r < 3; ++r)
            #pragma unroll
            for (int j = 0; j < 3; ++j) {
                float e = __expf(lg[r * 3 + j] - m);
                s += e;
                o += e * vb[r][wi + j];
            }
        ov[wi] = o * __builtin_amdgcn_rcpf(s);
    }

    size_t oi = ((size_t)b * COUT + c) * HWSZ + h * 64 + w0;
    *(floatx4*)(out + oi)     = (floatx4){ ov[0], ov[1], ov[2], ov[3] };
    *(floatx4*)(out + oi + 4) = (floatx4){ ov[4], ov[5], ov[6], ov[7] };
}

extern "C" void kernel_launch(void* const* d_in, const int* in_sizes, int n_in,
                              void* d_out, int out_size, void* d_ws, size_t ws_size,
                              hipStream_t stream) {
    const float* x = (const float*)d_in[0];
    const float* y = (const float*)d_in[1];
    const float* wq = (const float*)d_in[2];
    const float* wk = (const float*)d_in[3];
    const float* wv = (const float*)d_in[4];
    const float* rel_h = (const float*)d_in[5];
    const float* rel_w = (const float*)d_in[6];
    float* out = (float*)d_out;

    char* ws = (char*)d_ws;
    unsigned short* wqb = (unsigned short*)(ws + 33554432);
    unsigned short* wkb = (unsigned short*)(ws + 33554432 + 131072);
    unsigned short* wvb = (unsigned short*)(ws + 33554432 + 262144);
    unsigned short* Qb  = (unsigned short*)(ws + 33947648);
    unsigned short* Kb  = (unsigned short*)(ws + 33947648 + 16777216);
    unsigned short* Vb  = (unsigned short*)(ws + 33947648 + 33554432);

    wcast<<<256, 256, 0, stream>>>(wq, wk, wv, wqb, wkb, wvb);
    gemm_qkv<<<dim3(256, 2, 3), 256, 0, stream>>>(wqb, wkb, wvb, x, y, Qb, Kb, Vb);
    attn<<<4096, 256, 0, stream>>>(Qb, Kb, Vb, rel_h, rel_w, out);
}